// Round 5
// baseline (531.417 us; speedup 1.0000x reference)
//
#include <hip/hip_runtime.h>
#include <math.h>

// DiffGatedTopK: x (16384 x 4096 fp32). Per row: k=614 top-k mask, gain =
// sigmoid(top1-top2)*3+1, out = x*mask*gain.
//
// Structure (R3 theory, R4 bugfix):
//   1. PLAIN stores (no NT) -- R3 showed all NT-store versions stall at
//      ~2.5 TB/s while a plain-store fill sustains 6.5 TB/s.
//   2. Persistent blocks (grid 2048, 8 rows/block) with NEXT-ROW REGISTER
//      PREFETCH: row n+1's loads are issued before row n's reduction/search,
//      keeping memory in flight through the compute phase.
//   3. 5-probe bracket fused into the load pass (quartiles of the k-th-stat
//      law N(1.0364, 0.024) for i.i.d. N(0,1) rows): 0.90, 1.020, 1.0364,
//      1.053, 1.17. Regula falsi inside the bracket -> count==K in ~1-3
//      passes.
// R4 BUG (absmax 3.81): bracket selection was inverted -- it picked the
// bracket BELOW the threshold whenever an inner probe count was still >= K.
// Correct rule: bracket at the FIRST probe whose count drops below K:
//   n1<K -> [P0,P1], n2<K -> [P1,P2], n3<K -> [P2,P3], else [P3,P4].
// Bracket misses / exact-duplicate ties fall to rare exact paths (lowest
// index first, matching jax.lax.top_k). All barriers block-uniform.

#define D     4096
#define K     614            // int(4096 * 0.15)
#define BLOCK 256
#define NW    4              // waves per block
#define NB    4              // float4 batches per lane (16 values/lane)
#define GRID  2048           // 16384 rows -> 8 rows/block, uniform trip

typedef float f32x4 __attribute__((ext_vector_type(4)));

__device__ __forceinline__ unsigned int f2ord(float f) {
    unsigned int b = __float_as_uint(f);
    return ((int)b >= 0) ? (b | 0x80000000u) : ~b;
}

__global__ __launch_bounds__(BLOCK, 8)
void diffgated_topk(const float* __restrict__ x, float* __restrict__ out, int rows) {
    const int tid  = threadIdx.x;
    const int lane = tid & 63;
    const int w    = tid >> 6;

    __shared__ float        sm1[NW], sm2[NW];
    __shared__ unsigned int scA[NW], scB[NW], scC[NW];
    __shared__ int          scnt[2][NW];              // parity double-buffer
    __shared__ int          eqc[NB][NW];

    // probes: guards at ~+-5.5 sigma, inner at quartiles of N(1.0364, 0.024)
    const float P0 = 0.90f, P1 = 1.020f, P2 = 1.0364f, P3 = 1.053f, P4 = 1.17f;

    // ---- prologue: load first row ----
    f32x4 vv[NB], pf[NB];
    if (blockIdx.x < (unsigned)rows) {
        const f32x4* xr = (const f32x4*)(x + (size_t)blockIdx.x * D);
        #pragma unroll
        for (int b = 0; b < NB; ++b) vv[b] = xr[b * 256 + tid];
    }

    for (int r = blockIdx.x; r < rows; r += gridDim.x) {
        // ---- issue next row's loads NOW (in flight through this row's work) ----
        const int rn = r + gridDim.x;
        if (rn < rows) {
            const f32x4* xn = (const f32x4*)(x + (size_t)rn * D);
            #pragma unroll
            for (int b = 0; b < NB; ++b) pf[b] = xn[b * 256 + tid];
        }
        f32x4* orow = (f32x4*)(out + (size_t)r * D);

        // ---- consume vv: per-lane top-2 + 5 probe counts ----
        float m1 = -INFINITY, m2 = -INFINITY;
        unsigned int cA = 0u, cB = 0u, cC = 0u;       // c0|c1<<16, c2|c3<<16, c4
        #pragma unroll
        for (int b = 0; b < NB; ++b) {
            #pragma unroll
            for (int j = 0; j < 4; ++j) {
                float q = vv[b][j];
                float lo2 = fminf(m1, q);
                m1 = fmaxf(m1, q);
                m2 = fmaxf(m2, lo2);
                cA += (q >= P0) ? 1u : 0u;
                cA += (q >= P1) ? 0x10000u : 0u;
                cB += (q >= P2) ? 1u : 0u;
                cB += (q >= P3) ? 0x10000u : 0u;
                cC += (q >= P4) ? 1u : 0u;
            }
        }

        // ---- wave butterfly ----
        #pragma unroll
        for (int off = 32; off; off >>= 1) {
            float o1 = __shfl_xor(m1, off);
            float o2 = __shfl_xor(m2, off);
            cA += __shfl_xor(cA, off);                // fields <=4096: no carry-cross
            cB += __shfl_xor(cB, off);
            cC += __shfl_xor(cC, off);
            float hi2 = fmaxf(m1, o1), lo2 = fminf(m1, o1);
            m2 = fmaxf(m2, fmaxf(lo2, o2));
            m1 = hi2;
        }

        // ---- cross-wave merge (pre-barrier protects prior row's LDS readers) ----
        __syncthreads();
        if (lane == 0) { sm1[w] = m1; sm2[w] = m2; scA[w] = cA; scB[w] = cB; scC[w] = cC; }
        __syncthreads();
        {
            float a1 = sm1[0], a2 = sm2[0];
            unsigned int tA = scA[0], tB = scB[0], tC = scC[0];
            #pragma unroll
            for (int i = 1; i < NW; ++i) {
                float b1 = sm1[i], b2 = sm2[i];
                float nn1 = fmaxf(a1, b1);
                float nn2 = fmaxf(fminf(a1, b1), fmaxf(a2, b2));
                a1 = nn1; a2 = nn2; tA += scA[i]; tB += scB[i]; tC += scC[i];
            }
            m1 = a1; m2 = a2; cA = tA; cB = tB; cC = tC;
        }
        const int n0 = (int)(cA & 0xFFFFu), n1 = (int)(cA >> 16);
        const int n2 = (int)(cB & 0xFFFFu), n3 = (int)(cB >> 16);
        const int n4 = (int)cC;
        const float gain = 3.0f / (1.0f + expf(-(m1 - m2))) + 1.0f;

        unsigned int ut_ord;                          // ordered k-th pattern
        int cnt_lo, cnt_hi;
        bool exact;

        if (n0 >= K && n4 < K) {
            // ==== HOT: bracket = first probe pair where count crosses K ====
            // counts decrease: n0 >= n1 >= n2 >= n3 >= n4.
            // invariant: cnt_lo = count(>=lo) >= K > cnt_hi = count(>=hi).
            unsigned int lo, hi;
            if      (n1 < K) { lo = __float_as_uint(P0); hi = __float_as_uint(P1); cnt_lo = n0; cnt_hi = n1; }
            else if (n2 < K) { lo = __float_as_uint(P1); hi = __float_as_uint(P2); cnt_lo = n1; cnt_hi = n2; }
            else if (n3 < K) { lo = __float_as_uint(P2); hi = __float_as_uint(P3); cnt_lo = n2; cnt_hi = n3; }
            else             { lo = __float_as_uint(P3); hi = __float_as_uint(P4); cnt_lo = n3; cnt_hi = n4; }
            int it = 0;
            while (hi - lo > 1u && cnt_lo != K) {
                unsigned int span = hi - lo;
                unsigned int mid;
                if (it & 1) {
                    mid = lo + (span >> 1);           // safeguard bisection
                } else {
                    float frac = (float)(cnt_lo - K) *
                                 __builtin_amdgcn_rcpf((float)(cnt_lo - cnt_hi));
                    unsigned int step = (unsigned int)((float)span * frac);
                    if (step < 1u)        step = 1u;
                    if (step > span - 1u) step = span - 1u;
                    mid = lo + step;
                }
                const float midf = __uint_as_float(mid);
                int cw = 0;
                #pragma unroll
                for (int b = 0; b < NB; ++b)
                    #pragma unroll
                    for (int j = 0; j < 4; ++j)
                        cw += (int)__popcll(__ballot(vv[b][j] >= midf));
                const int p = it & 1;
                if (lane == 0) scnt[p][w] = cw;
                __syncthreads();
                int cnt = scnt[p][0] + scnt[p][1] + scnt[p][2] + scnt[p][3];
                if (cnt >= K) { lo = mid; cnt_lo = cnt; }
                else          { hi = mid; cnt_hi = cnt; }
                ++it;
            }
            ut_ord = lo | 0x80000000u;                // positive float -> ordered
            exact = (cnt_lo == K);
            if (exact) {
                const float tf = __uint_as_float(lo);
                #pragma unroll
                for (int b = 0; b < NB; ++b) {
                    f32x4 o;
                    #pragma unroll
                    for (int j = 0; j < 4; ++j) {
                        float q = vv[b][j];
                        o[j] = (q >= tf) ? q * gain : 0.0f;
                    }
                    orow[b * 256 + tid] = o;          // plain store
                }
            }
        } else {
            // ==== COLD: fully-general ordered-domain bisection ====
            unsigned long long lo = 0ull, hi = 0x100000000ull;
            cnt_lo = D; cnt_hi = 0;
            int it = 0;
            while (hi - lo > 1ull && cnt_lo != K) {
                unsigned int mid = (unsigned int)((lo + hi) >> 1);
                int cw = 0;
                for (int b = 0; b < NB; ++b)
                    for (int j = 0; j < 4; ++j)
                        cw += (int)__popcll(__ballot(f2ord(vv[b][j]) >= mid));
                const int p = it & 1;
                if (lane == 0) scnt[p][w] = cw;
                __syncthreads();
                int cnt = scnt[p][0] + scnt[p][1] + scnt[p][2] + scnt[p][3];
                if (cnt >= K) { lo = mid; cnt_lo = cnt; }
                else          { hi = mid; cnt_hi = cnt; }
                ++it;
            }
            ut_ord = (unsigned int)lo;
            exact = (cnt_lo == K);
            if (exact) {
                #pragma unroll
                for (int b = 0; b < NB; ++b) {
                    f32x4 o;
                    #pragma unroll
                    for (int j = 0; j < 4; ++j) {
                        float q = vv[b][j];
                        o[j] = (f2ord(q) >= ut_ord) ? q * gain : 0.0f;
                    }
                    orow[b * 256 + tid] = o;
                }
            }
        }

        if (!exact) {
            // ==== RARE: exact-duplicate ties straddle rank K ====
            // lowest global index first (matches jax.lax.top_k). Element
            // global index = 1024*b + 256*w + 4*lane + j.
            const int needed = K - cnt_hi;            // #equals to include (>=1)
            const unsigned long long ltmask =
                (lane == 0) ? 0ull : ((~0ull) >> (64 - lane));
            #pragma unroll
            for (int b = 0; b < NB; ++b) {
                int e = 0;
                #pragma unroll
                for (int j = 0; j < 4; ++j)
                    e += (int)__popcll(__ballot(f2ord(vv[b][j]) == ut_ord));
                if (lane == 0) eqc[b][w] = e;
            }
            __syncthreads();
            int base = 0;
            #pragma unroll
            for (int b = 0; b < NB; ++b) {
                int pre = base;
                for (int wp = 0; wp < w; ++wp) pre += eqc[b][wp];
                unsigned long long bal[4];
                #pragma unroll
                for (int j = 0; j < 4; ++j)
                    bal[j] = __ballot(f2ord(vv[b][j]) == ut_ord);
                f32x4 o;
                #pragma unroll
                for (int j = 0; j < 4; ++j) {
                    float q = vv[b][j];
                    unsigned int uo = f2ord(q);
                    float f = 0.0f;
                    if (uo > ut_ord) {
                        f = q * gain;
                    } else if (uo == ut_ord) {
                        int rk = pre;
                        #pragma unroll
                        for (int j2 = 0; j2 < 4; ++j2) {
                            rk += (int)__popcll(bal[j2] & ltmask);
                            if (j2 < j) rk += (int)((bal[j2] >> lane) & 1ull);
                        }
                        if (rk < needed) f = q * gain;
                    }
                    o[j] = f;
                }
                orow[b * 256 + tid] = o;
                int tot = 0;
                #pragma unroll
                for (int wp = 0; wp < NW; ++wp) tot += eqc[b][wp];
                base += tot;
            }
        }

        // ---- rotate prefetch -> current ----
        #pragma unroll
        for (int b = 0; b < NB; ++b) vv[b] = pf[b];
    }
}

extern "C" void kernel_launch(void* const* d_in, const int* in_sizes, int n_in,
                              void* d_out, int out_size, void* d_ws, size_t ws_size,
                              hipStream_t stream) {
    const float* x = (const float*)d_in[0];
    float* out = (float*)d_out;
    const int rows = in_sizes[0] / D;                 // 16384
    diffgated_topk<<<dim3(GRID), dim3(BLOCK), 0, stream>>>(x, out, rows);
}